// Round 4
// baseline (204.228 us; speedup 1.0000x reference)
//
#include <hip/hip_runtime.h>
#include <hip/hip_bf16.h>

// Problem constants (fixed by reference setup_inputs)
#define M 4096
#define N 8192
#define D 128

typedef __attribute__((ext_vector_type(8))) short short8_t;   // 8 bf16 (MFMA A/B frag)
typedef __attribute__((ext_vector_type(16))) float f32x16;    // 32x32 MFMA C/D frag

__device__ inline unsigned short f2bf(float f) {
    union { float f; unsigned u; } v; v.f = f;
    unsigned r = v.u + 0x7FFFu + ((v.u >> 16) & 1u);
    return (unsigned short)(r >> 16);
}

// ws layout (floats):  sxn[M] | axn[N] | sxb_t (M*64 dwords) | axb_t (N*64 dwords)
__global__ __launch_bounds__(256) void prep_kernel(const float* __restrict__ sub_x,
                                                   const float* __restrict__ all_x,
                                                   float* __restrict__ ws,
                                                   float* __restrict__ out) {
    const int wave = threadIdx.x >> 6;
    const int lane = threadIdx.x & 63;
    const int row  = blockIdx.x * 4 + wave;

    unsigned* sxb = (unsigned*)(ws + M + N);
    unsigned* axb = sxb + (size_t)M * 64;

    const float* src; float* ndst; unsigned* tdst; int r, R;
    if (row < M) { r = row;     src = sub_x + (size_t)r * D; ndst = ws + r;     tdst = sxb; R = M; }
    else         { r = row - M; src = all_x + (size_t)r * D; ndst = ws + M + r; tdst = axb; R = N; }

    const float2 v = ((const float2*)src)[lane];

    float s = v.x * v.x + v.y * v.y;
    #pragma unroll
    for (int off = 32; off > 0; off >>= 1) s += __shfl_down(s, off, 64);
    if (lane == 0) ndst[0] = s;

    const unsigned p = ((unsigned)f2bf(v.y) << 16) | (unsigned)f2bf(v.x);
    const int k8 = lane >> 2, q = lane & 3;
    tdst[((size_t)k8 * R + r) * 4 + q] = p;

    if (blockIdx.x == 0 && threadIdx.x == 0) out[0] = 0.0f;
}

// R10: R7 structure, but ALL in-loop VMEM is inline-asm with hand-counted vmcnt.
// Per phase jt: issue b(jt) x8 (L2, dwordx4), issue gv(jt+1) x16 (HBM, dword),
// s_waitcnt vmcnt(16)  [b(jt) + gv(jt) complete; gv(jt+1) stays in flight through
// MFMA + epilogue + next phase's issue], MFMA x8, epilogue. Consumed registers are
// threaded "+v" through the wait asm so the compiler cannot hoist consumers past it.
// Zero compiler-managed VMEM in the loop => zero compiler-inserted vmcnt waits.

// asm load: dst <- mem[sbase + (vbase + DELTA)]; DELTA is a compile-time literal.
#define GLOAD(dst, vb, DELTA, sb)                                          \
  { unsigned _t;                                                           \
    asm volatile("v_add_u32 %1, %3, %2\n\t"                                \
                 "global_load_dword %0, %1, %4"                            \
                 : "=v"(dst), "=&v"(_t)                                    \
                 : "v"(vb), "i"(DELTA), "s"(sb)); }

#define BLOAD(dst, vb, DELTA, sb)                                          \
  { unsigned _t;                                                           \
    asm volatile("v_add_u32 %1, %3, %2\n\t"                                \
                 "global_load_dwordx4 %0, %1, %4"                          \
                 : "=v"(dst), "=&v"(_t)                                    \
                 : "v"(vb), "i"(DELTA), "s"(sb)); }

#define B8(JT)                                                             \
  BLOAD(b[0], vbB, 0 * N * 32 + (JT) * 512, axp)                           \
  BLOAD(b[1], vbB, 1 * N * 32 + (JT) * 512, axp)                           \
  BLOAD(b[2], vbB, 2 * N * 32 + (JT) * 512, axp)                           \
  BLOAD(b[3], vbB, 3 * N * 32 + (JT) * 512, axp)                           \
  BLOAD(b[4], vbB, 4 * N * 32 + (JT) * 512, axp)                           \
  BLOAD(b[5], vbB, 5 * N * 32 + (JT) * 512, axp)                           \
  BLOAD(b[6], vbB, 6 * N * 32 + (JT) * 512, axp)                           \
  BLOAD(b[7], vbB, 7 * N * 32 + (JT) * 512, axp)

// row offset for acc slot r: (r&3) + 8*(r>>2); byte delta = rowoff*N*4 + JN*128
#define G1(GV, R, JN)                                                      \
  GLOAD(GV[R], vbG, ((((R) & 3) + 8 * ((R) >> 2)) * N * 4 + (JN) * 128), Gp)
#define G16(GV, JN)                                                        \
  G1(GV, 0, JN)  G1(GV, 1, JN)  G1(GV, 2, JN)  G1(GV, 3, JN)               \
  G1(GV, 4, JN)  G1(GV, 5, JN)  G1(GV, 6, JN)  G1(GV, 7, JN)               \
  G1(GV, 8, JN)  G1(GV, 9, JN)  G1(GV, 10, JN) G1(GV, 11, JN)              \
  G1(GV, 12, JN) G1(GV, 13, JN) G1(GV, 14, JN) G1(GV, 15, JN)

// counted wait; threads every register consumed below it (data-dep pins order)
#define WAITP(NSTR, GV)                                                    \
  asm volatile("s_waitcnt vmcnt(" NSTR ")"                                 \
    : "+v"(b[0]), "+v"(b[1]), "+v"(b[2]), "+v"(b[3]),                      \
      "+v"(b[4]), "+v"(b[5]), "+v"(b[6]), "+v"(b[7]),                      \
      "+v"(GV[0]),  "+v"(GV[1]),  "+v"(GV[2]),  "+v"(GV[3]),               \
      "+v"(GV[4]),  "+v"(GV[5]),  "+v"(GV[6]),  "+v"(GV[7]),               \
      "+v"(GV[8]),  "+v"(GV[9]),  "+v"(GV[10]), "+v"(GV[11]),              \
      "+v"(GV[12]), "+v"(GV[13]), "+v"(GV[14]), "+v"(GV[15]));

#define PHASE_TAIL(JT, GVC)                                                \
    f32x16 acc;                                                            \
    _Pragma("unroll")                                                      \
    for (int r = 0; r < 16; ++r) acc[r] = 0.0f;                            \
    _Pragma("unroll")                                                      \
    for (int kk = 0; kk < 8; ++kk)                                         \
      acc = __builtin_amdgcn_mfma_f32_32x32x16_bf16(a_frag[kk], b[kk], acc, 0, 0, 0); \
    const float av = axv[JT];                                              \
    _Pragma("unroll")                                                      \
    for (int r = 0; r < 16; ++r)                                           \
      local += GVC[r] * (sxv[r] + av - 2.0f * acc[r]);

#define PHASE(JT, GVC, GVN)                                                \
  { B8(JT) G16(GVN, (JT) + 1) WAITP("16", GVC) PHASE_TAIL(JT, GVC) }

#define PHASEL(JT, GVC)                                                    \
  { B8(JT) WAITP("0", GVC) PHASE_TAIL(JT, GVC) }

__global__ __launch_bounds__(256, 3) void graph_loss_kernel(const float* __restrict__ G,
                                                            const float* __restrict__ ws,
                                                            float* __restrict__ out) {
    __shared__ float red[4];

    const int tid  = threadIdx.x;
    const int lane = tid & 63;
    const int w    = tid >> 6;
    const int c    = lane & 31;
    const int hw   = lane >> 5;

    const int ti = blockIdx.x >> 6;   // 0..31
    const int tj = blockIdx.x & 63;   // 0..63
    const int i0 = ti * 128;
    const int j0 = tj * 128;

    const float* sxn = ws;
    const float* axn = ws + M;
    const uint4* sxb = (const uint4*)(ws + M + N);
    const uint4* axb = sxb + (size_t)16 * M;

    // ---- compiler-managed prologue loads (drained once, before the asm pipeline) ----
    short8_t a_frag[8];
    #pragma unroll
    for (int kk = 0; kk < 8; ++kk) {
        const uint4 t = sxb[(size_t)(kk * 2 + hw) * M + i0 + w * 32 + c];
        a_frag[kk] = *(const short8_t*)&t;
    }
    float sxv[16];
    #pragma unroll
    for (int r = 0; r < 16; ++r)
        sxv[r] = sxn[i0 + w * 32 + (r & 3) + 8 * (r >> 2) + 4 * hw];
    float axv[4];
    #pragma unroll
    for (int jt = 0; jt < 4; ++jt)
        axv[jt] = axn[j0 + jt * 32 + c];

    // fence: keep compiler loads above, asm pipeline below
    asm volatile("" ::: "memory");

    // ---- asm pipeline state ----
    const unsigned long long Gp  = (unsigned long long)G;
    const unsigned long long axp = (unsigned long long)axb;
    const unsigned vbG = (unsigned)((((size_t)(i0 + w * 32 + 4 * hw)) * N + j0 + c) * 4);
    const unsigned vbB = (unsigned)(((size_t)hw * N + j0 + c) * 16);

    short8_t b[8];
    float gA[16], gB[16];
    float local = 0.0f;

    G16(gA, 0)            // gv(0) in flight

    PHASE(0, gA, gB)
    PHASE(1, gB, gA)
    PHASE(2, gA, gB)
    PHASEL(3, gB)

    // ---- Reduce: wave shuffle -> LDS -> one atomic per block (pre-scaled; /2^25 exact) ----
    #pragma unroll
    for (int off = 32; off > 0; off >>= 1) local += __shfl_down(local, off, 64);
    if (lane == 0) red[w] = local;
    __syncthreads();
    if (tid == 0) {
        const float bsum = red[0] + red[1] + red[2] + red[3];
        atomicAdd(out, bsum * (1.0f / 33554432.0f));   // / (m*n) = / 2^25
    }
}

extern "C" void kernel_launch(void* const* d_in, const int* in_sizes, int n_in,
                              void* d_out, int out_size, void* d_ws, size_t ws_size,
                              hipStream_t stream) {
    const float* G      = (const float*)d_in[0];  // [M,N]
    const float* sub_x  = (const float*)d_in[1];  // [M,D]
    const float* all_x  = (const float*)d_in[2];  // [N,D]
    float* out = (float*)d_out;
    float* ws  = (float*)d_ws;

    prep_kernel<<<(M + N) / 4, 256, 0, stream>>>(sub_x, all_x, ws, out);
    graph_loss_kernel<<<(M / 128) * (N / 128), 256, 0, stream>>>(G, ws, out);
}